// Round 1
// baseline (4672.464 us; speedup 1.0000x reference)
//
#include <hip/hip_runtime.h>
#include <hip/hip_bf16.h>

#define NEG_SLOPE 0.1f
#define D1 128
#define D2 256

__device__ __forceinline__ float leaky(float x) { return x >= 0.f ? x : NEG_SLOPE * x; }

// ---- stage 1: per-source-node edge stats: count + sum(|val|) ----
__global__ void k_edge_stats(const int* __restrict__ row, const float* __restrict__ val,
                             float* __restrict__ cnt, float* __restrict__ abs_sum, int E)
{
    int e = blockIdx.x * blockDim.x + threadIdx.x;
    if (e >= E) return;
    int r = row[e];
    atomicAdd(&cnt[r], 1.0f);
    atomicAdd(&abs_sum[r], fabsf(val[e]));
}

// ---- stage 2: per-node: abs_mean, deg, dinv, self-loop pv ----
__global__ void k_node_stats(const float* __restrict__ cnt, const float* __restrict__ abs_sum,
                             float* __restrict__ dinv, float* __restrict__ pv_self, int N)
{
    int i = blockIdx.x * blockDim.x + threadIdx.x;
    if (i >= N) return;
    float c  = cnt[i];
    float as = abs_sum[i];
    float am = as / fmaxf(c, 1.0f);           // scatter-mean of |val| over source rows
    float deg = as + am;                      // sum|fval| grouped by frow (edges + self)
    float di  = deg > 0.f ? rsqrtf(deg) : 0.f;
    dinv[i]    = di;
    pv_self[i] = am * di * di;                // self-loop normalized value
}

// ---- stage 3: per-edge pv + conv1 output accumulation (x = ones) ----
__global__ void k_pv_x1(const int* __restrict__ row, const int* __restrict__ col,
                        const float* __restrict__ val, const float* __restrict__ dinv,
                        float* __restrict__ pv, float* __restrict__ x1, int E)
{
    int e = blockIdx.x * blockDim.x + threadIdx.x;
    if (e >= E) return;
    int r = row[e], c = col[e];
    float p = val[e] * dinv[r] * dinv[c];
    pv[e] = p;
    atomicAdd(&x1[c], p);
}

__global__ void k_x1_self(const float* __restrict__ pv_self, float* __restrict__ x1, int N)
{
    int i = blockIdx.x * blockDim.x + threadIdx.x;
    if (i >= N) return;
    x1[i] += pv_self[i];                      // conv1 out = sum(pv into col) incl. self
}

// ---- stage 4: h1 = leaky(x1 * w1^T + b1)  (N,1)x(1,128) ----
__global__ void k_h1(const float* __restrict__ x1, const float* __restrict__ w1,
                     const float* __restrict__ b1, float* __restrict__ h1, int N)
{
    int t = blockIdx.x * blockDim.x + threadIdx.x;
    if (t >= N * D1) return;
    int i = t >> 7, d = t & 127;
    h1[t] = leaky(x1[i] * w1[d] + b1[d]);
}

// ---- propagate init: dst[i,:] = pv_self[i] * src[i,:] (also covers 0xAA poison) ----
__global__ void k_prop_init(const float* __restrict__ pv_self, const float* __restrict__ src,
                            float* __restrict__ dst, int N)
{
    int t = blockIdx.x * blockDim.x + threadIdx.x;
    if (t >= N * D1) return;
    int i = t >> 7;
    dst[t] = pv_self[i] * src[t];
}

// ---- propagate edges: dst[col,:] += pv[e] * src[row,:]  (128-dim) ----
__global__ void k_prop_edges(const int* __restrict__ row, const int* __restrict__ col,
                             const float* __restrict__ pv, const float* __restrict__ src,
                             float* __restrict__ dst, int E)
{
    int t = blockIdx.x * blockDim.x + threadIdx.x;
    if (t >= E * D1) return;       // E*128 = 204.8M < 2^31
    int e = t >> 7, d = t & 127;
    int r = row[e], c = col[e];
    float p = pv[e];
    atomicAdd(&dst[c * D1 + d], p * src[r * D1 + d]);
}

// ---- conv2 tail: h2 = leaky(W2 * p2 + x1*b2 + bias2), W2 is (256,128) ----
__global__ __launch_bounds__(256) void k_gemm2(const float* __restrict__ p2, const float* __restrict__ w2,
                                               const float* __restrict__ b2, const float* __restrict__ bias2,
                                               const float* __restrict__ x1, float* __restrict__ h2, int N)
{
    __shared__ float xs[D1];
    int i = blockIdx.x;
    int m = threadIdx.x;
    if (m < D1) xs[m] = p2[i * D1 + m];
    __syncthreads();
    const float* wr = w2 + m * D1;
    float acc = 0.f;
#pragma unroll 8
    for (int k = 0; k < D1; k++) acc += wr[k] * xs[k];
    acc += x1[i] * b2[m] + bias2[m];
    h2[i * D2 + m] = leaky(acc);
}

// ---- conv3 linear: z = W3 * h2 + b3, W3 is (128,256) ----
__global__ __launch_bounds__(128) void k_gemm3(const float* __restrict__ h2, const float* __restrict__ w3,
                                               const float* __restrict__ b3, float* __restrict__ z, int N)
{
    __shared__ float xs[D2];
    int i = blockIdx.x;
    int m = threadIdx.x;
    xs[m] = h2[i * D2 + m];
    xs[m + D1] = h2[i * D2 + m + D1];
    __syncthreads();
    const float* wr = w3 + m * D2;
    float acc = 0.f;
#pragma unroll 8
    for (int k = 0; k < D2; k++) acc += wr[k] * xs[k];
    z[i * D1 + m] = acc + b3[m];
}

// ---- final: out = leaky(out + bias3) ----
__global__ void k_finalize(float* __restrict__ out, const float* __restrict__ bias3, int N)
{
    int t = blockIdx.x * blockDim.x + threadIdx.x;
    if (t >= N * D1) return;
    int d = t & 127;
    out[t] = leaky(out[t] + bias3[d]);
}

extern "C" void kernel_launch(void* const* d_in, const int* in_sizes, int n_in,
                              void* d_out, int out_size, void* d_ws, size_t ws_size,
                              hipStream_t stream)
{
    const int* ei       = (const int*)d_in[0];     // (2,E) int32
    const float* val    = (const float*)d_in[1];   // (E,)
    const float* w1     = (const float*)d_in[3];   // (128,1)
    const float* b1     = (const float*)d_in[4];   // (128,)
    const float* w2     = (const float*)d_in[5];   // (256,128)
    const float* b2     = (const float*)d_in[6];   // (256,)
    const float* bias2  = (const float*)d_in[7];   // (256,)
    const float* w3     = (const float*)d_in[8];   // (128,256)
    const float* b3     = (const float*)d_in[9];   // (128,)
    const float* bias3  = (const float*)d_in[10];  // (128,)
    float* out = (float*)d_out;

    const int E = in_sizes[1];
    const int N = out_size / D1;
    const int* row = ei;
    const int* col = ei + E;

    // workspace layout (floats)
    float* ws      = (float*)d_ws;
    float* cnt     = ws;                 // N  (zeroed)
    float* abs_sum = ws + (size_t)N;     // N  (zeroed)
    float* x1      = ws + (size_t)2*N;   // N  (zeroed)
    float* dinv    = ws + (size_t)3*N;   // N
    float* pv_self = ws + (size_t)4*N;   // N
    float* pv      = ws + (size_t)5*N;   // E
    float* h1      = pv + (size_t)E;         // N*128
    float* p2      = h1 + (size_t)N*D1;      // N*128
    float* h2      = p2 + (size_t)N*D1;      // N*256
    float* z       = h1;                     // reuse h1 (dead after gemm2's input p2 built)

    hipMemsetAsync(ws, 0, (size_t)3 * N * sizeof(float), stream);

    const int B = 256;
    k_edge_stats<<<(E + B - 1) / B, B, 0, stream>>>(row, val, cnt, abs_sum, E);
    k_node_stats<<<(N + B - 1) / B, B, 0, stream>>>(cnt, abs_sum, dinv, pv_self, N);
    k_pv_x1<<<(E + B - 1) / B, B, 0, stream>>>(row, col, val, dinv, pv, x1, E);
    k_x1_self<<<(N + B - 1) / B, B, 0, stream>>>(pv_self, x1, N);
    k_h1<<<((size_t)N * D1 + B - 1) / B, B, 0, stream>>>(x1, w1, b1, h1, N);

    // conv2: propagate h1 (128-dim), then GEMM 128->256 with x1*b2 correction
    k_prop_init<<<((size_t)N * D1 + B - 1) / B, B, 0, stream>>>(pv_self, h1, p2, N);
    k_prop_edges<<<((size_t)E * D1 + B - 1) / B, B, 0, stream>>>(row, col, pv, h1, p2, E);
    k_gemm2<<<N, 256, 0, stream>>>(p2, w2, b2, bias2, x1, h2, N);

    // conv3: GEMM 256->128 per node, then propagate z (128-dim)
    k_gemm3<<<N, 128, 0, stream>>>(h2, w3, b3, z, N);
    k_prop_init<<<((size_t)N * D1 + B - 1) / B, B, 0, stream>>>(pv_self, z, out, N);
    k_prop_edges<<<((size_t)E * D1 + B - 1) / B, B, 0, stream>>>(row, col, pv, z, out, E);
    k_finalize<<<((size_t)N * D1 + B - 1) / B, B, 0, stream>>>(out, bias3, N);
}

// Round 2
// 1968.000 us; speedup vs baseline: 2.3742x; 2.3742x over previous
//
#include <hip/hip_runtime.h>
#include <hip/hip_bf16.h>

#define NEG_SLOPE 0.1f
#define D1 128
#define D2 256

__device__ __forceinline__ float leaky(float x) { return x >= 0.f ? x : NEG_SLOPE * x; }

// ---- stage 1: per-source-node edge stats: count + sum(|val|) ----
__global__ void k_edge_stats(const int* __restrict__ row, const float* __restrict__ val,
                             float* __restrict__ cnt, float* __restrict__ abs_sum, int E)
{
    int e = blockIdx.x * blockDim.x + threadIdx.x;
    if (e >= E) return;
    int r = row[e];
    atomicAdd(&cnt[r], 1.0f);
    atomicAdd(&abs_sum[r], fabsf(val[e]));
}

// ---- stage 2: per-node: abs_mean, deg, dinv, self-loop pv ----
__global__ void k_node_stats(const float* __restrict__ cnt, const float* __restrict__ abs_sum,
                             float* __restrict__ dinv, float* __restrict__ pv_self, int N)
{
    int i = blockIdx.x * blockDim.x + threadIdx.x;
    if (i >= N) return;
    float c  = cnt[i];
    float as = abs_sum[i];
    float am = as / fmaxf(c, 1.0f);           // scatter-mean of |val| over source rows
    float deg = as + am;                      // sum|fval| grouped by frow (edges + self)
    float di  = deg > 0.f ? rsqrtf(deg) : 0.f;
    dinv[i]    = di;
    pv_self[i] = am * di * di;                // self-loop normalized value
}

// ---- stage 3: per-edge pv + conv1 output accumulation (x = ones) ----
__global__ void k_pv_x1(const int* __restrict__ row, const int* __restrict__ col,
                        const float* __restrict__ val, const float* __restrict__ dinv,
                        float* __restrict__ pv, float* __restrict__ x1, int E)
{
    int e = blockIdx.x * blockDim.x + threadIdx.x;
    if (e >= E) return;
    int r = row[e], c = col[e];
    float p = val[e] * dinv[r] * dinv[c];
    pv[e] = p;
    atomicAdd(&x1[c], p);
}

__global__ void k_x1_self(const float* __restrict__ pv_self, float* __restrict__ x1, int N)
{
    int i = blockIdx.x * blockDim.x + threadIdx.x;
    if (i >= N) return;
    x1[i] += pv_self[i];                      // conv1 out = sum(pv into col) incl. self
}

// ---- stage 4: h1 = leaky(x1 * w1^T + b1)  (N,1)x(1,128) ----
__global__ void k_h1(const float* __restrict__ x1, const float* __restrict__ w1,
                     const float* __restrict__ b1, float* __restrict__ h1, int N)
{
    int t = blockIdx.x * blockDim.x + threadIdx.x;
    if (t >= N * D1) return;
    int i = t >> 7, d = t & 127;
    h1[t] = leaky(x1[i] * w1[d] + b1[d]);
}

// ---- propagate init: dst[i,:] = pv_self[i] * src[i,:] (also covers 0xAA poison) ----
__global__ void k_prop_init(const float* __restrict__ pv_self, const float* __restrict__ src,
                            float* __restrict__ dst, int N)
{
    int t = blockIdx.x * blockDim.x + threadIdx.x;
    if (t >= N * D1) return;
    int i = t >> 7;
    dst[t] = pv_self[i] * src[t];
}

// ---- propagate edges: dst[col,:] += pv[e] * src[row,:]  (128-dim) ----
__global__ void k_prop_edges(const int* __restrict__ row, const int* __restrict__ col,
                             const float* __restrict__ pv, const float* __restrict__ src,
                             float* __restrict__ dst, int E)
{
    int t = blockIdx.x * blockDim.x + threadIdx.x;
    if (t >= E * D1) return;       // E*128 = 204.8M < 2^31
    int e = t >> 7, d = t & 127;
    int r = row[e], c = col[e];
    float p = pv[e];
    atomicAdd(&dst[c * D1 + d], p * src[r * D1 + d]);
}

// ---- tiled fp32 GEMM: C[N x M] = X[N x K] * W^T (+ epilogue), W is (M,K) row-major
// TM=64 nodes x TN=64 cols per 256-thread block, BK=16, 4x4 micro-tile.
// X1B: epilogue adds x1[node]*bvec[m] + bias[m]; else adds bvec[m].
template<int K, int M, bool LEAKY, bool X1B>
__global__ __launch_bounds__(256) void k_gemm_t(const float* __restrict__ X,
                                                const float* __restrict__ W,
                                                const float* __restrict__ bvec,
                                                const float* __restrict__ bias,
                                                const float* __restrict__ x1,
                                                float* __restrict__ C, int N)
{
    __shared__ float Xs[16][64];   // [k][node], transposed chunk
    __shared__ float Ws[16][64];   // [k][col],  transposed chunk

    const int tid = threadIdx.x;
    const int tc  = tid & 15;        // col group  (4 cols each)
    const int tr  = tid >> 4;        // node group (4 nodes each)
    const int n_base = blockIdx.x * 64;
    const int m_base = blockIdx.y * 64;

    float acc[4][4] = {};

    // staging: each thread loads one float4 of X and one float4 of W per chunk
    const int ld_row = tid >> 2;          // 0..63
    const int ld_k4  = (tid & 3) * 4;     // 0,4,8,12
    const int xnode  = n_base + ld_row;
    const bool xok   = xnode < N;
    const float* Xrow = X + (size_t)xnode * K + ld_k4;
    const float* Wrow = W + (size_t)(m_base + ld_row) * K + ld_k4;

    for (int k0 = 0; k0 < K; k0 += 16) {
        float4 xv = xok ? *(const float4*)(Xrow + k0) : make_float4(0.f, 0.f, 0.f, 0.f);
        float4 wv = *(const float4*)(Wrow + k0);
        __syncthreads();
        Xs[ld_k4 + 0][ld_row] = xv.x;
        Xs[ld_k4 + 1][ld_row] = xv.y;
        Xs[ld_k4 + 2][ld_row] = xv.z;
        Xs[ld_k4 + 3][ld_row] = xv.w;
        Ws[ld_k4 + 0][ld_row] = wv.x;
        Ws[ld_k4 + 1][ld_row] = wv.y;
        Ws[ld_k4 + 2][ld_row] = wv.z;
        Ws[ld_k4 + 3][ld_row] = wv.w;
        __syncthreads();
#pragma unroll
        for (int k = 0; k < 16; k++) {
            float4 a = *(const float4*)&Xs[k][tr * 4];
            float4 b = *(const float4*)&Ws[k][tc * 4];
            acc[0][0] += a.x * b.x; acc[0][1] += a.x * b.y; acc[0][2] += a.x * b.z; acc[0][3] += a.x * b.w;
            acc[1][0] += a.y * b.x; acc[1][1] += a.y * b.y; acc[1][2] += a.y * b.z; acc[1][3] += a.y * b.w;
            acc[2][0] += a.z * b.x; acc[2][1] += a.z * b.y; acc[2][2] += a.z * b.z; acc[2][3] += a.z * b.w;
            acc[3][0] += a.w * b.x; acc[3][1] += a.w * b.y; acc[3][2] += a.w * b.z; acc[3][3] += a.w * b.w;
        }
    }

#pragma unroll
    for (int ii = 0; ii < 4; ii++) {
        int node = n_base + tr * 4 + ii;
        if (node >= N) continue;
        float x1v = X1B ? x1[node] : 0.f;
#pragma unroll
        for (int jj = 0; jj < 4; jj++) {
            int m = m_base + tc * 4 + jj;
            float v = acc[ii][jj];
            if (X1B) v += x1v * bvec[m] + bias[m];
            else     v += bvec[m];
            if (LEAKY) v = leaky(v);
            C[(size_t)node * M + m] = v;
        }
    }
}

// ---- final: out = leaky(out + bias3) ----
__global__ void k_finalize(float* __restrict__ out, const float* __restrict__ bias3, int N)
{
    int t = blockIdx.x * blockDim.x + threadIdx.x;
    if (t >= N * D1) return;
    int d = t & 127;
    out[t] = leaky(out[t] + bias3[d]);
}

extern "C" void kernel_launch(void* const* d_in, const int* in_sizes, int n_in,
                              void* d_out, int out_size, void* d_ws, size_t ws_size,
                              hipStream_t stream)
{
    const int* ei       = (const int*)d_in[0];     // (2,E) int32
    const float* val    = (const float*)d_in[1];   // (E,)
    const float* w1     = (const float*)d_in[3];   // (128,1)
    const float* b1     = (const float*)d_in[4];   // (128,)
    const float* w2     = (const float*)d_in[5];   // (256,128)
    const float* b2     = (const float*)d_in[6];   // (256,)
    const float* bias2  = (const float*)d_in[7];   // (256,)
    const float* w3     = (const float*)d_in[8];   // (128,256)
    const float* b3     = (const float*)d_in[9];   // (128,)
    const float* bias3  = (const float*)d_in[10];  // (128,)
    float* out = (float*)d_out;

    const int E = in_sizes[1];
    const int N = out_size / D1;
    const int* row = ei;
    const int* col = ei + E;

    // workspace layout (floats)
    float* ws      = (float*)d_ws;
    float* cnt     = ws;                 // N  (zeroed)
    float* abs_sum = ws + (size_t)N;     // N  (zeroed)
    float* x1      = ws + (size_t)2*N;   // N  (zeroed)
    float* dinv    = ws + (size_t)3*N;   // N
    float* pv_self = ws + (size_t)4*N;   // N
    float* pv      = ws + (size_t)5*N;   // E
    float* h1      = pv + (size_t)E;         // N*128
    float* p2      = h1 + (size_t)N*D1;      // N*128
    float* h2      = p2 + (size_t)N*D1;      // N*256
    float* z       = h1;                     // reuse h1 (dead after p2 built)

    hipMemsetAsync(ws, 0, (size_t)3 * N * sizeof(float), stream);

    const int B = 256;
    k_edge_stats<<<(E + B - 1) / B, B, 0, stream>>>(row, val, cnt, abs_sum, E);
    k_node_stats<<<(N + B - 1) / B, B, 0, stream>>>(cnt, abs_sum, dinv, pv_self, N);
    k_pv_x1<<<(E + B - 1) / B, B, 0, stream>>>(row, col, val, dinv, pv, x1, E);
    k_x1_self<<<(N + B - 1) / B, B, 0, stream>>>(pv_self, x1, N);
    k_h1<<<((size_t)N * D1 + B - 1) / B, B, 0, stream>>>(x1, w1, b1, h1, N);

    // conv2: propagate h1 (128-dim), then GEMM 128->256 with x1*b2 correction
    k_prop_init<<<((size_t)N * D1 + B - 1) / B, B, 0, stream>>>(pv_self, h1, p2, N);
    k_prop_edges<<<((size_t)E * D1 + B - 1) / B, B, 0, stream>>>(row, col, pv, h1, p2, E);
    {
        dim3 grid((N + 63) / 64, D2 / 64);
        k_gemm_t<D1, D2, true, true><<<grid, 256, 0, stream>>>(p2, w2, b2, bias2, x1, h2, N);
    }

    // conv3: GEMM 256->128 per node, then propagate z (128-dim)
    {
        dim3 grid((N + 63) / 64, D1 / 64);
        k_gemm_t<D2, D1, false, false><<<grid, 256, 0, stream>>>(h2, w3, b3, nullptr, nullptr, z, N);
    }
    k_prop_init<<<((size_t)N * D1 + B - 1) / B, B, 0, stream>>>(pv_self, z, out, N);
    k_prop_edges<<<((size_t)E * D1 + B - 1) / B, B, 0, stream>>>(row, col, pv, z, out, E);
    k_finalize<<<((size_t)N * D1 + B - 1) / B, B, 0, stream>>>(out, bias3, N);
}

// Round 3
// 1217.503 us; speedup vs baseline: 3.8377x; 1.6164x over previous
//
#include <hip/hip_runtime.h>
#include <hip/hip_bf16.h>

#define NEG_SLOPE 0.1f
#define D1 128
#define D2 256

__device__ __forceinline__ float leaky(float x) { return x >= 0.f ? x : NEG_SLOPE * x; }

// ---- stage 1: per-edge stats: row count + row sum(|val|) + col histogram ----
__global__ void k_edge_stats(const int* __restrict__ row, const int* __restrict__ col,
                             const float* __restrict__ val,
                             float* __restrict__ cnt, float* __restrict__ abs_sum,
                             int* __restrict__ col_cnt, int E)
{
    int e = blockIdx.x * blockDim.x + threadIdx.x;
    if (e >= E) return;
    int r = row[e];
    atomicAdd(&cnt[r], 1.0f);
    atomicAdd(&abs_sum[r], fabsf(val[e]));
    atomicAdd(&col_cnt[col[e]], 1);
}

// ---- stage 2: per-node: abs_mean, deg, dinv, self-loop pv ----
__global__ void k_node_stats(const float* __restrict__ cnt, const float* __restrict__ abs_sum,
                             float* __restrict__ dinv, float* __restrict__ pv_self, int N)
{
    int i = blockIdx.x * blockDim.x + threadIdx.x;
    if (i >= N) return;
    float c  = cnt[i];
    float as = abs_sum[i];
    float am = as / fmaxf(c, 1.0f);           // scatter-mean of |val| over source rows
    float deg = as + am;                      // sum|fval| grouped by frow (edges + self)
    float di  = deg > 0.f ? rsqrtf(deg) : 0.f;
    dinv[i]    = di;
    pv_self[i] = am * di * di;                // self-loop normalized value
}

// ---- exclusive scan of col_cnt -> col_ptr (2048 elems per 256-thread block) ----
__global__ __launch_bounds__(256) void k_scan_local(const int* __restrict__ in, int* __restrict__ out,
                                                    int* __restrict__ partials, int n)
{
    __shared__ int s[256];
    int base = blockIdx.x * 2048 + threadIdx.x * 8;
    int v[8]; int sum = 0;
#pragma unroll
    for (int i = 0; i < 8; i++) { v[i] = (base + i < n) ? in[base + i] : 0; sum += v[i]; }
    s[threadIdx.x] = sum;
    __syncthreads();
    for (int off = 1; off < 256; off <<= 1) {
        int t = (threadIdx.x >= off) ? s[threadIdx.x - off] : 0;
        __syncthreads();
        s[threadIdx.x] += t;
        __syncthreads();
    }
    int excl = s[threadIdx.x] - sum;
#pragma unroll
    for (int i = 0; i < 8; i++) { if (base + i < n) { out[base + i] = excl; excl += v[i]; } }
    if (threadIdx.x == 255) partials[blockIdx.x] = s[255];
}

__global__ void k_scan_partials(int* __restrict__ partials, int nb, int* __restrict__ col_ptr,
                                int n, int total)
{
    if (threadIdx.x == 0) {
        int run = 0;
        for (int i = 0; i < nb; i++) { int t = partials[i]; partials[i] = run; run += t; }
        col_ptr[n] = total;
    }
}

__global__ void k_scan_add(int* __restrict__ out, const int* __restrict__ partials, int n)
{
    int i = blockIdx.x * blockDim.x + threadIdx.x;
    if (i < n) out[i] += partials[i >> 11];
}

// ---- scatter edges into dest-sorted CSR: (srt_row, srt_pv) ----
__global__ void k_scatter(const int* __restrict__ row, const int* __restrict__ col,
                          const float* __restrict__ val, const float* __restrict__ dinv,
                          const int* __restrict__ col_ptr, int* __restrict__ fill,
                          int* __restrict__ srt_row, float* __restrict__ srt_pv, int E)
{
    int e = blockIdx.x * blockDim.x + threadIdx.x;
    if (e >= E) return;
    int r = row[e], c = col[e];
    float p = val[e] * dinv[r] * dinv[c];
    int pos = col_ptr[c] + atomicAdd(&fill[c], 1);
    srt_row[pos] = r;
    srt_pv[pos]  = p;
}

// ---- x1[i] = pv_self[i] + sum of srt_pv over CSR range (conv1 output, x = ones) ----
__global__ void k_x1(const int* __restrict__ col_ptr, const float* __restrict__ srt_pv,
                     const float* __restrict__ pv_self, float* __restrict__ x1, int N)
{
    int i = blockIdx.x * blockDim.x + threadIdx.x;
    if (i >= N) return;
    int s = col_ptr[i], e = col_ptr[i + 1];
    float acc = pv_self[i];
    for (int j = s; j < e; j++) acc += srt_pv[j];
    x1[i] = acc;
}

// ---- h1 = leaky(x1 * w1^T + b1) ----
__global__ void k_h1(const float* __restrict__ x1, const float* __restrict__ w1,
                     const float* __restrict__ b1, float* __restrict__ h1, int N)
{
    int t = blockIdx.x * blockDim.x + threadIdx.x;
    if (t >= N * D1) return;
    int i = t >> 7, d = t & 127;
    h1[t] = leaky(x1[i] * w1[d] + b1[d]);
}

// ---- gather propagate: dst[i,:] = pv_self[i]*src[i,:] + sum_j pv_j * src[row_j,:] ----
// 2 nodes per 256-thread block, 128 threads per node. FINAL fuses +bias3, leaky.
template<bool FINAL>
__global__ __launch_bounds__(256) void k_prop_gather(const int* __restrict__ col_ptr,
                                                     const int* __restrict__ srt_row,
                                                     const float* __restrict__ srt_pv,
                                                     const float* __restrict__ pv_self,
                                                     const float* __restrict__ src,
                                                     const float* __restrict__ bias3,
                                                     float* __restrict__ dst, int N)
{
    int node = blockIdx.x * 2 + (threadIdx.x >> 7);
    int d = threadIdx.x & 127;
    if (node >= N) return;
    float acc = pv_self[node] * src[(size_t)node * D1 + d];
    int s = col_ptr[node], e = col_ptr[node + 1];
    for (int j = s; j < e; j++) {
        int r = srt_row[j];
        float p = srt_pv[j];
        acc += p * src[(size_t)r * D1 + d];
    }
    if (FINAL) acc = leaky(acc + bias3[d]);
    dst[(size_t)node * D1 + d] = acc;
}

// ---- tiled fp32 GEMM: C[N x M] = X[N x K] * W^T (+ epilogue), W is (M,K) row-major
template<int K, int M, bool LEAKY, bool X1B>
__global__ __launch_bounds__(256) void k_gemm_t(const float* __restrict__ X,
                                                const float* __restrict__ W,
                                                const float* __restrict__ bvec,
                                                const float* __restrict__ bias,
                                                const float* __restrict__ x1,
                                                float* __restrict__ C, int N)
{
    __shared__ float Xs[16][64];   // [k][node]
    __shared__ float Ws[16][64];   // [k][col]

    const int tid = threadIdx.x;
    const int tc  = tid & 15;
    const int tr  = tid >> 4;
    const int n_base = blockIdx.x * 64;
    const int m_base = blockIdx.y * 64;

    float acc[4][4] = {};

    const int ld_row = tid >> 2;
    const int ld_k4  = (tid & 3) * 4;
    const int xnode  = n_base + ld_row;
    const bool xok   = xnode < N;
    const float* Xrow = X + (size_t)xnode * K + ld_k4;
    const float* Wrow = W + (size_t)(m_base + ld_row) * K + ld_k4;

    for (int k0 = 0; k0 < K; k0 += 16) {
        float4 xv = xok ? *(const float4*)(Xrow + k0) : make_float4(0.f, 0.f, 0.f, 0.f);
        float4 wv = *(const float4*)(Wrow + k0);
        __syncthreads();
        Xs[ld_k4 + 0][ld_row] = xv.x;
        Xs[ld_k4 + 1][ld_row] = xv.y;
        Xs[ld_k4 + 2][ld_row] = xv.z;
        Xs[ld_k4 + 3][ld_row] = xv.w;
        Ws[ld_k4 + 0][ld_row] = wv.x;
        Ws[ld_k4 + 1][ld_row] = wv.y;
        Ws[ld_k4 + 2][ld_row] = wv.z;
        Ws[ld_k4 + 3][ld_row] = wv.w;
        __syncthreads();
#pragma unroll
        for (int k = 0; k < 16; k++) {
            float4 a = *(const float4*)&Xs[k][tr * 4];
            float4 b = *(const float4*)&Ws[k][tc * 4];
            acc[0][0] += a.x * b.x; acc[0][1] += a.x * b.y; acc[0][2] += a.x * b.z; acc[0][3] += a.x * b.w;
            acc[1][0] += a.y * b.x; acc[1][1] += a.y * b.y; acc[1][2] += a.y * b.z; acc[1][3] += a.y * b.w;
            acc[2][0] += a.z * b.x; acc[2][1] += a.z * b.y; acc[2][2] += a.z * b.z; acc[2][3] += a.z * b.w;
            acc[3][0] += a.w * b.x; acc[3][1] += a.w * b.y; acc[3][2] += a.w * b.z; acc[3][3] += a.w * b.w;
        }
    }

#pragma unroll
    for (int ii = 0; ii < 4; ii++) {
        int node = n_base + tr * 4 + ii;
        if (node >= N) continue;
        float x1v = X1B ? x1[node] : 0.f;
#pragma unroll
        for (int jj = 0; jj < 4; jj++) {
            int m = m_base + tc * 4 + jj;
            float v = acc[ii][jj];
            if (X1B) v += x1v * bvec[m] + bias[m];
            else     v += bvec[m];
            if (LEAKY) v = leaky(v);
            C[(size_t)node * M + m] = v;
        }
    }
}

extern "C" void kernel_launch(void* const* d_in, const int* in_sizes, int n_in,
                              void* d_out, int out_size, void* d_ws, size_t ws_size,
                              hipStream_t stream)
{
    const int* ei       = (const int*)d_in[0];     // (2,E) int32
    const float* val    = (const float*)d_in[1];   // (E,)
    const float* w1     = (const float*)d_in[3];   // (128,1)
    const float* b1     = (const float*)d_in[4];   // (128,)
    const float* w2     = (const float*)d_in[5];   // (256,128)
    const float* b2     = (const float*)d_in[6];   // (256,)
    const float* bias2  = (const float*)d_in[7];   // (256,)
    const float* w3     = (const float*)d_in[8];   // (128,256)
    const float* b3     = (const float*)d_in[9];   // (128,)
    const float* bias3  = (const float*)d_in[10];  // (128,)
    float* out = (float*)d_out;

    const int E = in_sizes[1];
    const int N = out_size / D1;
    const int* row = ei;
    const int* col = ei + E;

    // workspace layout
    float* ws      = (float*)d_ws;
    float* cnt     = ws;                   // N  (zeroed)
    float* abs_sum = ws + (size_t)N;       // N  (zeroed)
    int*   col_cnt = (int*)(ws + (size_t)2*N);  // N (zeroed)
    int*   fill    = (int*)(ws + (size_t)3*N);  // N (zeroed)
    float* dinv    = ws + (size_t)4*N;     // N
    float* pv_self = ws + (size_t)5*N;     // N
    float* x1      = ws + (size_t)6*N;     // N
    int*   col_ptr = (int*)(ws + (size_t)7*N);  // N+1
    int*   partials= col_ptr + (size_t)N + 8;   // ~64
    int*   srt_row = partials + 64;             // E
    float* srt_pv  = (float*)(srt_row + (size_t)E); // E
    float* h1      = srt_pv + (size_t)E;        // N*128
    float* p2      = h1 + (size_t)N*D1;         // N*128
    float* h2      = p2 + (size_t)N*D1;         // N*256
    float* z       = h1;                        // reuse h1 (dead after p2 built)

    hipMemsetAsync(ws, 0, (size_t)4 * N * sizeof(float), stream);

    const int B = 256;
    const int scan_blocks = (N + 2047) / 2048;

    k_edge_stats<<<(E + B - 1) / B, B, 0, stream>>>(row, col, val, cnt, abs_sum, col_cnt, E);
    k_node_stats<<<(N + B - 1) / B, B, 0, stream>>>(cnt, abs_sum, dinv, pv_self, N);

    // exclusive scan col_cnt -> col_ptr
    k_scan_local<<<scan_blocks, 256, 0, stream>>>(col_cnt, col_ptr, partials, N);
    k_scan_partials<<<1, 64, 0, stream>>>(partials, scan_blocks, col_ptr, N, E);
    k_scan_add<<<(N + B - 1) / B, B, 0, stream>>>(col_ptr, partials, N);

    k_scatter<<<(E + B - 1) / B, B, 0, stream>>>(row, col, val, dinv, col_ptr, fill, srt_row, srt_pv, E);
    k_x1<<<(N + B - 1) / B, B, 0, stream>>>(col_ptr, srt_pv, pv_self, x1, N);
    k_h1<<<((size_t)N * D1 + B - 1) / B, B, 0, stream>>>(x1, w1, b1, h1, N);

    // conv2: propagate h1 (gather), then GEMM 128->256 with x1*b2 correction
    k_prop_gather<false><<<(N + 1) / 2, 256, 0, stream>>>(col_ptr, srt_row, srt_pv, pv_self, h1, nullptr, p2, N);
    {
        dim3 grid((N + 63) / 64, D2 / 64);
        k_gemm_t<D1, D2, true, true><<<grid, 256, 0, stream>>>(p2, w2, b2, bias2, x1, h2, N);
    }

    // conv3: GEMM 256->128 per node, then propagate z (gather) with fused bias3+leaky
    {
        dim3 grid((N + 63) / 64, D1 / 64);
        k_gemm_t<D2, D1, false, false><<<grid, 256, 0, stream>>>(h2, w3, b3, nullptr, nullptr, z, N);
    }
    k_prop_gather<true><<<(N + 1) / 2, 256, 0, stream>>>(col_ptr, srt_row, srt_pv, pv_self, z, bias3, out, N);
}

// Round 4
// 1032.315 us; speedup vs baseline: 4.5262x; 1.1794x over previous
//
#include <hip/hip_runtime.h>
#include <hip/hip_bf16.h>

#define NEG_SLOPE 0.1f
#define D1 128
#define D2 256

__device__ __forceinline__ float leaky(float x) { return x >= 0.f ? x : NEG_SLOPE * x; }

// ---- stage 1: per-edge stats: row count + row sum(|val|) + col histogram ----
__global__ void k_edge_stats(const int* __restrict__ row, const int* __restrict__ col,
                             const float* __restrict__ val,
                             float* __restrict__ cnt, float* __restrict__ abs_sum,
                             int* __restrict__ col_cnt, int E)
{
    int e = blockIdx.x * blockDim.x + threadIdx.x;
    if (e >= E) return;
    int r = row[e];
    atomicAdd(&cnt[r], 1.0f);
    atomicAdd(&abs_sum[r], fabsf(val[e]));
    atomicAdd(&col_cnt[col[e]], 1);
}

// ---- stage 2: per-node: abs_mean, deg, dinv, self-loop pv ----
__global__ void k_node_stats(const float* __restrict__ cnt, const float* __restrict__ abs_sum,
                             float* __restrict__ dinv, float* __restrict__ pv_self, int N)
{
    int i = blockIdx.x * blockDim.x + threadIdx.x;
    if (i >= N) return;
    float c  = cnt[i];
    float as = abs_sum[i];
    float am = as / fmaxf(c, 1.0f);           // scatter-mean of |val| over source rows
    float deg = as + am;                      // sum|fval| grouped by frow (edges + self)
    float di  = deg > 0.f ? rsqrtf(deg) : 0.f;
    dinv[i]    = di;
    pv_self[i] = am * di * di;                // self-loop normalized value
}

// ---- exclusive scan of col_cnt -> col_ptr (2048 elems per 256-thread block) ----
__global__ __launch_bounds__(256) void k_scan_local(const int* __restrict__ in, int* __restrict__ out,
                                                    int* __restrict__ partials, int n)
{
    __shared__ int s[256];
    int base = blockIdx.x * 2048 + threadIdx.x * 8;
    int v[8]; int sum = 0;
#pragma unroll
    for (int i = 0; i < 8; i++) { v[i] = (base + i < n) ? in[base + i] : 0; sum += v[i]; }
    s[threadIdx.x] = sum;
    __syncthreads();
    for (int off = 1; off < 256; off <<= 1) {
        int t = (threadIdx.x >= off) ? s[threadIdx.x - off] : 0;
        __syncthreads();
        s[threadIdx.x] += t;
        __syncthreads();
    }
    int excl = s[threadIdx.x] - sum;
#pragma unroll
    for (int i = 0; i < 8; i++) { if (base + i < n) { out[base + i] = excl; excl += v[i]; } }
    if (threadIdx.x == 255) partials[blockIdx.x] = s[255];
}

__global__ void k_scan_partials(int* __restrict__ partials, int nb, int* __restrict__ col_ptr,
                                int n, int total)
{
    if (threadIdx.x == 0) {
        int run = 0;
        for (int i = 0; i < nb; i++) { int t = partials[i]; partials[i] = run; run += t; }
        col_ptr[n] = total;
    }
}

__global__ void k_scan_add(int* __restrict__ out, const int* __restrict__ partials, int n)
{
    int i = blockIdx.x * blockDim.x + threadIdx.x;
    if (i < n) out[i] += partials[i >> 11];
}

// ---- scatter edges into dest-sorted CSR: (srt_row, srt_pv) ----
__global__ void k_scatter(const int* __restrict__ row, const int* __restrict__ col,
                          const float* __restrict__ val, const float* __restrict__ dinv,
                          const int* __restrict__ col_ptr, int* __restrict__ fill,
                          int* __restrict__ srt_row, float* __restrict__ srt_pv, int E)
{
    int e = blockIdx.x * blockDim.x + threadIdx.x;
    if (e >= E) return;
    int r = row[e], c = col[e];
    float p = val[e] * dinv[r] * dinv[c];
    int pos = col_ptr[c] + atomicAdd(&fill[c], 1);
    srt_row[pos] = r;
    srt_pv[pos]  = p;
}

// ---- x1[i] = pv_self[i] + sum of srt_pv over CSR range (conv1 output, x = ones) ----
__global__ void k_x1(const int* __restrict__ col_ptr, const float* __restrict__ srt_pv,
                     const float* __restrict__ pv_self, float* __restrict__ x1, int N)
{
    int i = blockIdx.x * blockDim.x + threadIdx.x;
    if (i >= N) return;
    int s = col_ptr[i], e = col_ptr[i + 1];
    float acc = pv_self[i];
    for (int j = s; j < e; j++) acc += srt_pv[j];
    x1[i] = acc;
}

// ---- pack edge-aligned (pv, x1[row]) stream for the scalar conv2 propagate ----
__global__ void k_gather_x1(const int* __restrict__ srt_row, const float* __restrict__ srt_pv,
                            const float* __restrict__ x1, float2* __restrict__ px, int E)
{
    int j = blockIdx.x * blockDim.x + threadIdx.x;
    if (j >= E) return;
    px[j] = make_float2(srt_pv[j], x1[srt_row[j]]);
}

// ---- conv2 propagate, scalar form:
// p2[i,d] = pv_self[i]*f_d(x1[i]) + sum_j pv_j * f_d(x1[r_j]),  f_d(s)=leaky(s*w1[d]+b1[d])
// 2 nodes per 256-thread block, 128 threads (dims) per node; per-edge data is 8 B broadcast.
__global__ __launch_bounds__(256) void k_prop2(const int* __restrict__ col_ptr,
                                               const float2* __restrict__ px,
                                               const float* __restrict__ pv_self,
                                               const float* __restrict__ x1,
                                               const float* __restrict__ w1,
                                               const float* __restrict__ b1,
                                               float* __restrict__ p2, int N)
{
    int node = blockIdx.x * 2 + (threadIdx.x >> 7);
    int d = threadIdx.x & 127;
    if (node >= N) return;
    float wd = w1[d], bd = b1[d];
    float acc = pv_self[node] * leaky(fmaf(x1[node], wd, bd));
    int s = col_ptr[node], e = col_ptr[node + 1];
    for (int j = s; j < e; j++) {
        float2 t = px[j];
        acc += t.x * leaky(fmaf(t.y, wd, bd));
    }
    p2[(size_t)node * D1 + d] = acc;
}

// ---- gather propagate (conv3): dst[i,:] = pv_self[i]*src[i,:] + sum_j pv_j*src[row_j,:]
// FINAL epilogue: leaky(acc + bias3).
template<bool FINAL>
__global__ __launch_bounds__(256) void k_prop_gather(const int* __restrict__ col_ptr,
                                                     const int* __restrict__ srt_row,
                                                     const float* __restrict__ srt_pv,
                                                     const float* __restrict__ pv_self,
                                                     const float* __restrict__ src,
                                                     const float* __restrict__ bias3,
                                                     float* __restrict__ dst, int N)
{
    int node = blockIdx.x * 2 + (threadIdx.x >> 7);
    int d = threadIdx.x & 127;
    if (node >= N) return;
    float acc = pv_self[node] * src[(size_t)node * D1 + d];
    int s = col_ptr[node], e = col_ptr[node + 1];
    for (int j = s; j < e; j++) {
        int r = srt_row[j];
        float p = srt_pv[j];
        acc += p * src[(size_t)r * D1 + d];
    }
    if (FINAL) acc = leaky(acc + bias3[d]);
    dst[(size_t)node * D1 + d] = acc;
}

// ---- tiled fp32 GEMM: C[N x M] = X[N x K] * W^T (+ epilogue), W is (M,K) row-major
template<int K, int M, bool LEAKY, bool X1B>
__global__ __launch_bounds__(256) void k_gemm_t(const float* __restrict__ X,
                                                const float* __restrict__ W,
                                                const float* __restrict__ bvec,
                                                const float* __restrict__ bias,
                                                const float* __restrict__ x1,
                                                float* __restrict__ C, int N)
{
    __shared__ float Xs[16][64];   // [k][node]
    __shared__ float Ws[16][64];   // [k][col]

    const int tid = threadIdx.x;
    const int tc  = tid & 15;
    const int tr  = tid >> 4;
    const int n_base = blockIdx.x * 64;
    const int m_base = blockIdx.y * 64;

    float acc[4][4] = {};

    const int ld_row = tid >> 2;
    const int ld_k4  = (tid & 3) * 4;
    const int xnode  = n_base + ld_row;
    const bool xok   = xnode < N;
    const float* Xrow = X + (size_t)xnode * K + ld_k4;
    const float* Wrow = W + (size_t)(m_base + ld_row) * K + ld_k4;

    for (int k0 = 0; k0 < K; k0 += 16) {
        float4 xv = xok ? *(const float4*)(Xrow + k0) : make_float4(0.f, 0.f, 0.f, 0.f);
        float4 wv = *(const float4*)(Wrow + k0);
        __syncthreads();
        Xs[ld_k4 + 0][ld_row] = xv.x;
        Xs[ld_k4 + 1][ld_row] = xv.y;
        Xs[ld_k4 + 2][ld_row] = xv.z;
        Xs[ld_k4 + 3][ld_row] = xv.w;
        Ws[ld_k4 + 0][ld_row] = wv.x;
        Ws[ld_k4 + 1][ld_row] = wv.y;
        Ws[ld_k4 + 2][ld_row] = wv.z;
        Ws[ld_k4 + 3][ld_row] = wv.w;
        __syncthreads();
#pragma unroll
        for (int k = 0; k < 16; k++) {
            float4 a = *(const float4*)&Xs[k][tr * 4];
            float4 b = *(const float4*)&Ws[k][tc * 4];
            acc[0][0] += a.x * b.x; acc[0][1] += a.x * b.y; acc[0][2] += a.x * b.z; acc[0][3] += a.x * b.w;
            acc[1][0] += a.y * b.x; acc[1][1] += a.y * b.y; acc[1][2] += a.y * b.z; acc[1][3] += a.y * b.w;
            acc[2][0] += a.z * b.x; acc[2][1] += a.z * b.y; acc[2][2] += a.z * b.z; acc[2][3] += a.z * b.w;
            acc[3][0] += a.w * b.x; acc[3][1] += a.w * b.y; acc[3][2] += a.w * b.z; acc[3][3] += a.w * b.w;
        }
    }

#pragma unroll
    for (int ii = 0; ii < 4; ii++) {
        int node = n_base + tr * 4 + ii;
        if (node >= N) continue;
        float x1v = X1B ? x1[node] : 0.f;
#pragma unroll
        for (int jj = 0; jj < 4; jj++) {
            int m = m_base + tc * 4 + jj;
            float v = acc[ii][jj];
            if (X1B) v += x1v * bvec[m] + bias[m];
            else     v += bvec[m];
            if (LEAKY) v = leaky(v);
            C[(size_t)node * M + m] = v;
        }
    }
}

extern "C" void kernel_launch(void* const* d_in, const int* in_sizes, int n_in,
                              void* d_out, int out_size, void* d_ws, size_t ws_size,
                              hipStream_t stream)
{
    const int* ei       = (const int*)d_in[0];     // (2,E) int32
    const float* val    = (const float*)d_in[1];   // (E,)
    const float* w1     = (const float*)d_in[3];   // (128,1)
    const float* b1     = (const float*)d_in[4];   // (128,)
    const float* w2     = (const float*)d_in[5];   // (256,128)
    const float* b2     = (const float*)d_in[6];   // (256,)
    const float* bias2  = (const float*)d_in[7];   // (256,)
    const float* w3     = (const float*)d_in[8];   // (128,256)
    const float* b3     = (const float*)d_in[9];   // (128,)
    const float* bias3  = (const float*)d_in[10];  // (128,)
    float* out = (float*)d_out;

    const int E = in_sizes[1];
    const int N = out_size / D1;
    const int* row = ei;
    const int* col = ei + E;

    // workspace layout
    float* ws      = (float*)d_ws;
    float* cnt     = ws;                   // N  (zeroed)
    float* abs_sum = ws + (size_t)N;       // N  (zeroed)
    int*   col_cnt = (int*)(ws + (size_t)2*N);  // N (zeroed)
    int*   fill    = (int*)(ws + (size_t)3*N);  // N (zeroed)
    float* dinv    = ws + (size_t)4*N;     // N
    float* pv_self = ws + (size_t)5*N;     // N
    float* x1      = ws + (size_t)6*N;     // N
    int*   col_ptr = (int*)(ws + (size_t)7*N);  // N+1
    int*   partials= col_ptr + (size_t)N + 8;   // ~64
    int*   srt_row = partials + 64;             // E
    float* srt_pv  = (float*)(srt_row + (size_t)E); // E
    float2* px     = (float2*)(srt_pv + (size_t)E); // E float2 (8B-aligned: offset even)
    float* p2      = (float*)(px + (size_t)E);  // N*128
    float* h2      = p2 + (size_t)N*D1;         // N*256
    float* z       = p2;                        // reuse p2 (dead after gemm2)

    hipMemsetAsync(ws, 0, (size_t)4 * N * sizeof(float), stream);

    const int B = 256;
    const int scan_blocks = (N + 2047) / 2048;

    k_edge_stats<<<(E + B - 1) / B, B, 0, stream>>>(row, col, val, cnt, abs_sum, col_cnt, E);
    k_node_stats<<<(N + B - 1) / B, B, 0, stream>>>(cnt, abs_sum, dinv, pv_self, N);

    // exclusive scan col_cnt -> col_ptr
    k_scan_local<<<scan_blocks, 256, 0, stream>>>(col_cnt, col_ptr, partials, N);
    k_scan_partials<<<1, 64, 0, stream>>>(partials, scan_blocks, col_ptr, N, E);
    k_scan_add<<<(N + B - 1) / B, B, 0, stream>>>(col_ptr, partials, N);

    k_scatter<<<(E + B - 1) / B, B, 0, stream>>>(row, col, val, dinv, col_ptr, fill, srt_row, srt_pv, E);
    k_x1<<<(N + B - 1) / B, B, 0, stream>>>(col_ptr, srt_pv, pv_self, x1, N);
    k_gather_x1<<<(E + B - 1) / B, B, 0, stream>>>(srt_row, srt_pv, x1, px, E);

    // conv2: scalar-form propagate (h1 never materialized), then GEMM 128->256
    k_prop2<<<(N + 1) / 2, 256, 0, stream>>>(col_ptr, px, pv_self, x1, w1, b1, p2, N);
    {
        dim3 grid((N + 63) / 64, D2 / 64);
        k_gemm_t<D1, D2, true, true><<<grid, 256, 0, stream>>>(p2, w2, b2, bias2, x1, h2, N);
    }

    // conv3: GEMM 256->128 per node, then gather propagate with fused bias3+leaky
    {
        dim3 grid((N + 63) / 64, D1 / 64);
        k_gemm_t<D2, D1, false, false><<<grid, 256, 0, stream>>>(h2, w3, b3, nullptr, nullptr, z, N);
    }
    k_prop_gather<true><<<(N + 1) / 2, 256, 0, stream>>>(col_ptr, srt_row, srt_pv, pv_self, z, bias3, out, N);
}

// Round 5
// 857.079 us; speedup vs baseline: 5.4516x; 1.2045x over previous
//
#include <hip/hip_runtime.h>
#include <hip/hip_bf16.h>

#define NEG_SLOPE 0.1f
#define D1 128
#define D2 256

__device__ __forceinline__ float leaky(float x) { return x >= 0.f ? x : NEG_SLOPE * x; }

__device__ __forceinline__ unsigned short f2bf(float x) {
    union { float f; unsigned int u; } v; v.f = x;
    unsigned int r = (v.u + 0x7FFFu + ((v.u >> 16) & 1u)) >> 16;   // RNE
    return (unsigned short)r;
}

// ---- stage 1: per-edge stats: row count + row sum(|val|) + col histogram ----
__global__ void k_edge_stats(const int* __restrict__ row, const int* __restrict__ col,
                             const float* __restrict__ val,
                             float* __restrict__ cnt, float* __restrict__ abs_sum,
                             int* __restrict__ col_cnt, int E)
{
    int e = blockIdx.x * blockDim.x + threadIdx.x;
    if (e >= E) return;
    int r = row[e];
    atomicAdd(&cnt[r], 1.0f);
    atomicAdd(&abs_sum[r], fabsf(val[e]));
    atomicAdd(&col_cnt[col[e]], 1);
}

// ---- stage 2: per-node: abs_mean, deg, dinv, self-loop pv ----
__global__ void k_node_stats(const float* __restrict__ cnt, const float* __restrict__ abs_sum,
                             float* __restrict__ dinv, float* __restrict__ pv_self, int N)
{
    int i = blockIdx.x * blockDim.x + threadIdx.x;
    if (i >= N) return;
    float c  = cnt[i];
    float as = abs_sum[i];
    float am = as / fmaxf(c, 1.0f);
    float deg = as + am;
    float di  = deg > 0.f ? rsqrtf(deg) : 0.f;
    dinv[i]    = di;
    pv_self[i] = am * di * di;
}

// ---- exclusive scan of col_cnt -> col_ptr ----
__global__ __launch_bounds__(256) void k_scan_local(const int* __restrict__ in, int* __restrict__ out,
                                                    int* __restrict__ partials, int n)
{
    __shared__ int s[256];
    int base = blockIdx.x * 2048 + threadIdx.x * 8;
    int v[8]; int sum = 0;
#pragma unroll
    for (int i = 0; i < 8; i++) { v[i] = (base + i < n) ? in[base + i] : 0; sum += v[i]; }
    s[threadIdx.x] = sum;
    __syncthreads();
    for (int off = 1; off < 256; off <<= 1) {
        int t = (threadIdx.x >= off) ? s[threadIdx.x - off] : 0;
        __syncthreads();
        s[threadIdx.x] += t;
        __syncthreads();
    }
    int excl = s[threadIdx.x] - sum;
#pragma unroll
    for (int i = 0; i < 8; i++) { if (base + i < n) { out[base + i] = excl; excl += v[i]; } }
    if (threadIdx.x == 255) partials[blockIdx.x] = s[255];
}

__global__ void k_scan_partials(int* __restrict__ partials, int nb, int* __restrict__ col_ptr,
                                int n, int total)
{
    if (threadIdx.x == 0) {
        int run = 0;
        for (int i = 0; i < nb; i++) { int t = partials[i]; partials[i] = run; run += t; }
        col_ptr[n] = total;
    }
}

__global__ void k_scan_add(int* __restrict__ out, const int* __restrict__ partials, int n)
{
    int i = blockIdx.x * blockDim.x + threadIdx.x;
    if (i < n) out[i] += partials[i >> 11];
}

// ---- scatter edges into dest-sorted CSR: packed (row, pv) ----
__global__ void k_scatter(const int* __restrict__ row, const int* __restrict__ col,
                          const float* __restrict__ val, const float* __restrict__ dinv,
                          const int* __restrict__ col_ptr, int* __restrict__ fill,
                          int2* __restrict__ srt_rp, int E)
{
    int e = blockIdx.x * blockDim.x + threadIdx.x;
    if (e >= E) return;
    int r = row[e], c = col[e];
    float p = val[e] * dinv[r] * dinv[c];
    int pos = col_ptr[c] + atomicAdd(&fill[c], 1);
    srt_rp[pos] = make_int2(r, __float_as_int(p));
}

// ---- x1[i] = pv_self[i] + sum of pv over CSR range ----
__global__ void k_x1(const int* __restrict__ col_ptr, const int2* __restrict__ srt_rp,
                     const float* __restrict__ pv_self, float* __restrict__ x1, int N)
{
    int i = blockIdx.x * blockDim.x + threadIdx.x;
    if (i >= N) return;
    int s = col_ptr[i], e = col_ptr[i + 1];
    float acc = pv_self[i];
    for (int j = s; j < e; j++) acc += __int_as_float(srt_rp[j].y);
    x1[i] = acc;
}

// ---- pack edge-aligned (pv, x1[row]) stream for the scalar conv2 propagate ----
__global__ void k_gather_x1(const int2* __restrict__ srt_rp,
                            const float* __restrict__ x1, float2* __restrict__ px, int E)
{
    int j = blockIdx.x * blockDim.x + threadIdx.x;
    if (j >= E) return;
    int2 rp = srt_rp[j];
    px[j] = make_float2(__int_as_float(rp.y), x1[rp.x]);
}

// ---- conv2 propagate, scalar form:
// p2[i,d] = pv_self[i]*f_d(x1[i]) + sum_j pv_j * f_d(x1[r_j]),  f_d(s)=leaky(s*w1[d]+b1[d])
__global__ __launch_bounds__(256) void k_prop2(const int* __restrict__ col_ptr,
                                               const float2* __restrict__ px,
                                               const float* __restrict__ pv_self,
                                               const float* __restrict__ x1,
                                               const float* __restrict__ w1,
                                               const float* __restrict__ b1,
                                               float* __restrict__ p2, int N)
{
    int node = blockIdx.x * 2 + (threadIdx.x >> 7);
    int d = threadIdx.x & 127;
    if (node >= N) return;
    float wd = w1[d], bd = b1[d];
    float acc = pv_self[node] * leaky(fmaf(x1[node], wd, bd));
    int s = col_ptr[node], e = col_ptr[node + 1];
    for (int j = s; j < e; j++) {
        float2 t = px[j];
        acc += t.x * leaky(fmaf(t.y, wd, bd));
    }
    p2[(size_t)node * D1 + d] = acc;
}

// ---- conv3 gather propagate over bf16 z, one wave per node, 2 dims per lane ----
// out[i,:] = leaky( pv_self[i]*z[i,:] + sum_j pv_j*z[row_j,:] + bias3 )
__global__ __launch_bounds__(256) void k_prop3_bf16(const int* __restrict__ col_ptr,
                                                    const int2* __restrict__ srt_rp,
                                                    const float* __restrict__ pv_self,
                                                    const unsigned int* __restrict__ zb, // N x 64 uints (2 bf16 each)
                                                    const float* __restrict__ bias3,
                                                    float* __restrict__ out, int N)
{
    int node = blockIdx.x * 4 + (threadIdx.x >> 6);
    int lane = threadIdx.x & 63;
    if (node >= N) return;

    unsigned int us = zb[(size_t)node * 64 + lane];
    float ps = pv_self[node];
    float acc0 = ps * __uint_as_float(us << 16);
    float acc1 = ps * __uint_as_float(us & 0xFFFF0000u);

    int j = col_ptr[node], e = col_ptr[node + 1];
    for (; j + 1 < e; j += 2) {
        int2 rp0 = srt_rp[j];
        int2 rp1 = srt_rp[j + 1];
        unsigned int u0 = zb[(size_t)rp0.x * 64 + lane];
        unsigned int u1 = zb[(size_t)rp1.x * 64 + lane];
        float p0 = __int_as_float(rp0.y);
        float p1 = __int_as_float(rp1.y);
        acc0 += p0 * __uint_as_float(u0 << 16);
        acc1 += p0 * __uint_as_float(u0 & 0xFFFF0000u);
        acc0 += p1 * __uint_as_float(u1 << 16);
        acc1 += p1 * __uint_as_float(u1 & 0xFFFF0000u);
    }
    if (j < e) {
        int2 rp = srt_rp[j];
        unsigned int u = zb[(size_t)rp.x * 64 + lane];
        float p = __int_as_float(rp.y);
        acc0 += p * __uint_as_float(u << 16);
        acc1 += p * __uint_as_float(u & 0xFFFF0000u);
    }

    float2 b = *(const float2*)&bias3[lane * 2];
    float2 o = make_float2(leaky(acc0 + b.x), leaky(acc1 + b.y));
    *(float2*)&out[(size_t)node * D1 + lane * 2] = o;
}

// ---- tiled fp32 GEMM: C[N x M] = X[N x K] * W^T (+ epilogue), W is (M,K) row-major
// BF16OUT: C stored as bf16 (ushort), else fp32.
template<int K, int M, bool LEAKY, bool X1B, bool BF16OUT>
__global__ __launch_bounds__(256) void k_gemm_t(const float* __restrict__ X,
                                                const float* __restrict__ W,
                                                const float* __restrict__ bvec,
                                                const float* __restrict__ bias,
                                                const float* __restrict__ x1,
                                                void* __restrict__ Cv, int N)
{
    __shared__ float Xs[16][64];   // [k][node]
    __shared__ float Ws[16][64];   // [k][col]

    const int tid = threadIdx.x;
    const int tc  = tid & 15;
    const int tr  = tid >> 4;
    const int n_base = blockIdx.x * 64;
    const int m_base = blockIdx.y * 64;

    float acc[4][4] = {};

    const int ld_row = tid >> 2;
    const int ld_k4  = (tid & 3) * 4;
    const int xnode  = n_base + ld_row;
    const bool xok   = xnode < N;
    const float* Xrow = X + (size_t)xnode * K + ld_k4;
    const float* Wrow = W + (size_t)(m_base + ld_row) * K + ld_k4;

    for (int k0 = 0; k0 < K; k0 += 16) {
        float4 xv = xok ? *(const float4*)(Xrow + k0) : make_float4(0.f, 0.f, 0.f, 0.f);
        float4 wv = *(const float4*)(Wrow + k0);
        __syncthreads();
        Xs[ld_k4 + 0][ld_row] = xv.x;
        Xs[ld_k4 + 1][ld_row] = xv.y;
        Xs[ld_k4 + 2][ld_row] = xv.z;
        Xs[ld_k4 + 3][ld_row] = xv.w;
        Ws[ld_k4 + 0][ld_row] = wv.x;
        Ws[ld_k4 + 1][ld_row] = wv.y;
        Ws[ld_k4 + 2][ld_row] = wv.z;
        Ws[ld_k4 + 3][ld_row] = wv.w;
        __syncthreads();
#pragma unroll
        for (int k = 0; k < 16; k++) {
            float4 a = *(const float4*)&Xs[k][tr * 4];
            float4 b = *(const float4*)&Ws[k][tc * 4];
            acc[0][0] += a.x * b.x; acc[0][1] += a.x * b.y; acc[0][2] += a.x * b.z; acc[0][3] += a.x * b.w;
            acc[1][0] += a.y * b.x; acc[1][1] += a.y * b.y; acc[1][2] += a.y * b.z; acc[1][3] += a.y * b.w;
            acc[2][0] += a.z * b.x; acc[2][1] += a.z * b.y; acc[2][2] += a.z * b.z; acc[2][3] += a.z * b.w;
            acc[3][0] += a.w * b.x; acc[3][1] += a.w * b.y; acc[3][2] += a.w * b.z; acc[3][3] += a.w * b.w;
        }
    }

#pragma unroll
    for (int ii = 0; ii < 4; ii++) {
        int node = n_base + tr * 4 + ii;
        if (node >= N) continue;
        float x1v = X1B ? x1[node] : 0.f;
        float vout[4];
#pragma unroll
        for (int jj = 0; jj < 4; jj++) {
            int m = m_base + tc * 4 + jj;
            float v = acc[ii][jj];
            if (X1B) v += x1v * bvec[m] + bias[m];
            else     v += bvec[m];
            if (LEAKY) v = leaky(v);
            vout[jj] = v;
        }
        if (BF16OUT) {
            ushort4 s4;
            s4.x = f2bf(vout[0]); s4.y = f2bf(vout[1]);
            s4.z = f2bf(vout[2]); s4.w = f2bf(vout[3]);
            *(ushort4*)((unsigned short*)Cv + (size_t)node * M + m_base + tc * 4) = s4;
        } else {
            *(float4*)((float*)Cv + (size_t)node * M + m_base + tc * 4) =
                make_float4(vout[0], vout[1], vout[2], vout[3]);
        }
    }
}

extern "C" void kernel_launch(void* const* d_in, const int* in_sizes, int n_in,
                              void* d_out, int out_size, void* d_ws, size_t ws_size,
                              hipStream_t stream)
{
    const int* ei       = (const int*)d_in[0];     // (2,E) int32
    const float* val    = (const float*)d_in[1];   // (E,)
    const float* w1     = (const float*)d_in[3];   // (128,1)
    const float* b1     = (const float*)d_in[4];   // (128,)
    const float* w2     = (const float*)d_in[5];   // (256,128)
    const float* b2     = (const float*)d_in[6];   // (256,)
    const float* bias2  = (const float*)d_in[7];   // (256,)
    const float* w3     = (const float*)d_in[8];   // (128,256)
    const float* b3     = (const float*)d_in[9];   // (128,)
    const float* bias3  = (const float*)d_in[10];  // (128,)
    float* out = (float*)d_out;

    const int E = in_sizes[1];
    const int N = out_size / D1;
    const int* row = ei;
    const int* col = ei + E;

    // workspace layout
    float* ws      = (float*)d_ws;
    float* cnt     = ws;                   // N  (zeroed)
    float* abs_sum = ws + (size_t)N;       // N  (zeroed)
    int*   col_cnt = (int*)(ws + (size_t)2*N);  // N (zeroed)
    int*   fill    = (int*)(ws + (size_t)3*N);  // N (zeroed)
    float* dinv    = ws + (size_t)4*N;     // N
    float* pv_self = ws + (size_t)5*N;     // N
    float* x1      = ws + (size_t)6*N;     // N
    int*   col_ptr = (int*)(ws + (size_t)7*N);  // N+1
    int*   partials= col_ptr + (size_t)N + 8;   // 64
    int2*  srt_rp  = (int2*)(partials + 64);    // E int2 (8B aligned)
    float2* px     = (float2*)(srt_rp + (size_t)E); // E float2
    float* p2      = (float*)(px + (size_t)E);  // N*128 fp32
    float* h2      = p2 + (size_t)N*D1;         // N*256 fp32
    unsigned int* zb = (unsigned int*)p2;       // N*64 uints (bf16 z), aliases dead p2

    hipMemsetAsync(ws, 0, (size_t)4 * N * sizeof(float), stream);

    const int B = 256;
    const int scan_blocks = (N + 2047) / 2048;

    k_edge_stats<<<(E + B - 1) / B, B, 0, stream>>>(row, col, val, cnt, abs_sum, col_cnt, E);
    k_node_stats<<<(N + B - 1) / B, B, 0, stream>>>(cnt, abs_sum, dinv, pv_self, N);

    k_scan_local<<<scan_blocks, 256, 0, stream>>>(col_cnt, col_ptr, partials, N);
    k_scan_partials<<<1, 64, 0, stream>>>(partials, scan_blocks, col_ptr, N, E);
    k_scan_add<<<(N + B - 1) / B, B, 0, stream>>>(col_ptr, partials, N);

    k_scatter<<<(E + B - 1) / B, B, 0, stream>>>(row, col, val, dinv, col_ptr, fill, srt_rp, E);
    k_x1<<<(N + B - 1) / B, B, 0, stream>>>(col_ptr, srt_rp, pv_self, x1, N);
    k_gather_x1<<<(E + B - 1) / B, B, 0, stream>>>(srt_rp, x1, px, E);

    // conv2: scalar-form propagate, then GEMM 128->256 (fp32 out)
    k_prop2<<<(N + 1) / 2, 256, 0, stream>>>(col_ptr, px, pv_self, x1, w1, b1, p2, N);
    {
        dim3 grid((N + 63) / 64, D2 / 64);
        k_gemm_t<D1, D2, true, true, false><<<grid, 256, 0, stream>>>(p2, w2, b2, bias2, x1, h2, N);
    }

    // conv3: GEMM 256->128 -> bf16 z, then bf16 gather propagate + fused bias3/leaky
    {
        dim3 grid((N + 63) / 64, D1 / 64);
        k_gemm_t<D2, D1, false, false, true><<<grid, 256, 0, stream>>>(h2, w3, b3, nullptr, nullptr, (void*)zb, N);
    }
    k_prop3_bf16<<<(N + 3) / 4, 256, 0, stream>>>(col_ptr, srt_rp, pv_self, zb, bias3, out, N);
}

// Round 6
// 755.894 us; speedup vs baseline: 6.1814x; 1.1339x over previous
//
#include <hip/hip_runtime.h>
#include <hip/hip_bf16.h>

#define NEG_SLOPE 0.1f
#define D1 128
#define D2 256

__device__ __forceinline__ float leaky(float x) { return x >= 0.f ? x : NEG_SLOPE * x; }

__device__ __forceinline__ unsigned short f2bf(float x) {
    union { float f; unsigned int u; } v; v.f = x;
    unsigned int r = (v.u + 0x7FFFu + ((v.u >> 16) & 1u)) >> 16;   // RNE
    return (unsigned short)r;
}

// ---- stage 1: per-edge stats ----
// row stats: packed u64 (count << 42 | fixed-point(abs_sum, 2^-24)), privatized
// per-XCD (agent-scope atomic -> stays in local L2, no fabric write-through).
// col histogram: device-scope atomic whose RETURN VALUE is the edge's rank
// within its destination segment (reused by k_scatter -> no fill atomic there).
__global__ void k_edge_stats(const int* __restrict__ row, const int* __restrict__ col,
                             const float* __restrict__ val,
                             unsigned long long* __restrict__ rowstats8,
                             int* __restrict__ col_cnt, int* __restrict__ rank, int E, int N)
{
    int e = blockIdx.x * blockDim.x + threadIdx.x;
    if (e >= E) return;
    // HW_REG_XCC_ID = 20, offset 0, size 32 -> simm16 = (31<<11)|20 = 63508
    unsigned xcc = (unsigned)__builtin_amdgcn_s_getreg(63508) & 7u;
    int r = row[e], c = col[e];
    float av = fabsf(val[e]);
    unsigned long long pk = (1ULL << 42) |
        (unsigned long long)__float2uint_rn(av * 16777216.0f);   // 2^24 fixed point
    __hip_atomic_fetch_add(&rowstats8[(size_t)xcc * N + r], pk,
                           __ATOMIC_RELAXED, __HIP_MEMORY_SCOPE_AGENT);
    rank[e] = atomicAdd(&col_cnt[c], 1);
}

// ---- stage 2: combine 8 per-XCD copies; per-node abs_mean, deg, dinv, self pv ----
__global__ void k_node_stats(const unsigned long long* __restrict__ rowstats8,
                             float* __restrict__ dinv, float* __restrict__ pv_self, int N)
{
    int i = blockIdx.x * blockDim.x + threadIdx.x;
    if (i >= N) return;
    unsigned long long t = 0;
#pragma unroll
    for (int x = 0; x < 8; x++) t += rowstats8[(size_t)x * N + i];
    float c  = (float)(t >> 42);
    float as = (float)(t & ((1ULL << 42) - 1)) * (1.0f / 16777216.0f);
    float am = as / fmaxf(c, 1.0f);
    float deg = as + am;
    float di  = deg > 0.f ? rsqrtf(deg) : 0.f;
    dinv[i]    = di;
    pv_self[i] = am * di * di;
}

// ---- exclusive scan of col_cnt -> col_ptr ----
__global__ __launch_bounds__(256) void k_scan_local(const int* __restrict__ in, int* __restrict__ out,
                                                    int* __restrict__ partials, int n)
{
    __shared__ int s[256];
    int base = blockIdx.x * 2048 + threadIdx.x * 8;
    int v[8]; int sum = 0;
#pragma unroll
    for (int i = 0; i < 8; i++) { v[i] = (base + i < n) ? in[base + i] : 0; sum += v[i]; }
    s[threadIdx.x] = sum;
    __syncthreads();
    for (int off = 1; off < 256; off <<= 1) {
        int t = (threadIdx.x >= off) ? s[threadIdx.x - off] : 0;
        __syncthreads();
        s[threadIdx.x] += t;
        __syncthreads();
    }
    int excl = s[threadIdx.x] - sum;
#pragma unroll
    for (int i = 0; i < 8; i++) { if (base + i < n) { out[base + i] = excl; excl += v[i]; } }
    if (threadIdx.x == 255) partials[blockIdx.x] = s[255];
}

__global__ void k_scan_partials(int* __restrict__ partials, int nb, int* __restrict__ col_ptr,
                                int n, int total)
{
    if (threadIdx.x == 0) {
        int run = 0;
        for (int i = 0; i < nb; i++) { int t = partials[i]; partials[i] = run; run += t; }
        col_ptr[n] = total;
    }
}

__global__ void k_scan_add(int* __restrict__ out, const int* __restrict__ partials, int n)
{
    int i = blockIdx.x * blockDim.x + threadIdx.x;
    if (i < n) out[i] += partials[i >> 11];
}

// ---- scatter edges into dest-sorted CSR using precomputed ranks (no atomics) ----
__global__ void k_scatter(const int* __restrict__ row, const int* __restrict__ col,
                          const float* __restrict__ val, const float* __restrict__ dinv,
                          const int* __restrict__ col_ptr, const int* __restrict__ rank,
                          int2* __restrict__ srt_rp, int E)
{
    int e = blockIdx.x * blockDim.x + threadIdx.x;
    if (e >= E) return;
    int r = row[e], c = col[e];
    float p = val[e] * dinv[r] * dinv[c];
    int pos = col_ptr[c] + rank[e];
    srt_rp[pos] = make_int2(r, __float_as_int(p));
}

// ---- x1[i] = pv_self[i] + sum of pv over CSR range ----
__global__ void k_x1(const int* __restrict__ col_ptr, const int2* __restrict__ srt_rp,
                     const float* __restrict__ pv_self, float* __restrict__ x1, int N)
{
    int i = blockIdx.x * blockDim.x + threadIdx.x;
    if (i >= N) return;
    int s = col_ptr[i], e = col_ptr[i + 1];
    float acc = pv_self[i];
    for (int j = s; j < e; j++) acc += __int_as_float(srt_rp[j].y);
    x1[i] = acc;
}

// ---- pack edge-aligned (pv, x1[row]) stream for the scalar conv2 propagate ----
__global__ void k_gather_x1(const int2* __restrict__ srt_rp,
                            const float* __restrict__ x1, float2* __restrict__ px, int E)
{
    int j = blockIdx.x * blockDim.x + threadIdx.x;
    if (j >= E) return;
    int2 rp = srt_rp[j];
    px[j] = make_float2(__int_as_float(rp.y), x1[rp.x]);
}

// ---- conv2 propagate, scalar form:
// p2[i,d] = pv_self[i]*f_d(x1[i]) + sum_j pv_j * f_d(x1[r_j]),  f_d(s)=leaky(s*w1[d]+b1[d])
__global__ __launch_bounds__(256) void k_prop2(const int* __restrict__ col_ptr,
                                               const float2* __restrict__ px,
                                               const float* __restrict__ pv_self,
                                               const float* __restrict__ x1,
                                               const float* __restrict__ w1,
                                               const float* __restrict__ b1,
                                               float* __restrict__ p2, int N)
{
    int node = blockIdx.x * 2 + (threadIdx.x >> 7);
    int d = threadIdx.x & 127;
    if (node >= N) return;
    float wd = w1[d], bd = b1[d];
    float acc = pv_self[node] * leaky(fmaf(x1[node], wd, bd));
    int s = col_ptr[node], e = col_ptr[node + 1];
    for (int j = s; j < e; j++) {
        float2 t = px[j];
        acc += t.x * leaky(fmaf(t.y, wd, bd));
    }
    p2[(size_t)node * D1 + d] = acc;
}

// ---- conv3 gather propagate over bf16 z, one wave per node, 2 dims per lane ----
__global__ __launch_bounds__(256) void k_prop3_bf16(const int* __restrict__ col_ptr,
                                                    const int2* __restrict__ srt_rp,
                                                    const float* __restrict__ pv_self,
                                                    const unsigned int* __restrict__ zb,
                                                    const float* __restrict__ bias3,
                                                    float* __restrict__ out, int N)
{
    int node = blockIdx.x * 4 + (threadIdx.x >> 6);
    int lane = threadIdx.x & 63;
    if (node >= N) return;

    unsigned int us = zb[(size_t)node * 64 + lane];
    float ps = pv_self[node];
    float acc0 = ps * __uint_as_float(us << 16);
    float acc1 = ps * __uint_as_float(us & 0xFFFF0000u);

    int j = col_ptr[node], e = col_ptr[node + 1];
    for (; j + 1 < e; j += 2) {
        int2 rp0 = srt_rp[j];
        int2 rp1 = srt_rp[j + 1];
        unsigned int u0 = zb[(size_t)rp0.x * 64 + lane];
        unsigned int u1 = zb[(size_t)rp1.x * 64 + lane];
        float p0 = __int_as_float(rp0.y);
        float p1 = __int_as_float(rp1.y);
        acc0 += p0 * __uint_as_float(u0 << 16);
        acc1 += p0 * __uint_as_float(u0 & 0xFFFF0000u);
        acc0 += p1 * __uint_as_float(u1 << 16);
        acc1 += p1 * __uint_as_float(u1 & 0xFFFF0000u);
    }
    if (j < e) {
        int2 rp = srt_rp[j];
        unsigned int u = zb[(size_t)rp.x * 64 + lane];
        float p = __int_as_float(rp.y);
        acc0 += p * __uint_as_float(u << 16);
        acc1 += p * __uint_as_float(u & 0xFFFF0000u);
    }

    float2 b = *(const float2*)&bias3[lane * 2];
    float2 o = make_float2(leaky(acc0 + b.x), leaky(acc1 + b.y));
    *(float2*)&out[(size_t)node * D1 + lane * 2] = o;
}

// ---- tiled fp32 GEMM: C[N x M] = X[N x K] * W^T (+ epilogue), W is (M,K) row-major
template<int K, int M, bool LEAKY, bool X1B, bool BF16OUT>
__global__ __launch_bounds__(256) void k_gemm_t(const float* __restrict__ X,
                                                const float* __restrict__ W,
                                                const float* __restrict__ bvec,
                                                const float* __restrict__ bias,
                                                const float* __restrict__ x1,
                                                void* __restrict__ Cv, int N)
{
    __shared__ float Xs[16][64];   // [k][node]
    __shared__ float Ws[16][64];   // [k][col]

    const int tid = threadIdx.x;
    const int tc  = tid & 15;
    const int tr  = tid >> 4;
    const int n_base = blockIdx.x * 64;
    const int m_base = blockIdx.y * 64;

    float acc[4][4] = {};

    const int ld_row = tid >> 2;
    const int ld_k4  = (tid & 3) * 4;
    const int xnode  = n_base + ld_row;
    const bool xok   = xnode < N;
    const float* Xrow = X + (size_t)xnode * K + ld_k4;
    const float* Wrow = W + (size_t)(m_base + ld_row) * K + ld_k4;

    for (int k0 = 0; k0 < K; k0 += 16) {
        float4 xv = xok ? *(const float4*)(Xrow + k0) : make_float4(0.f, 0.f, 0.f, 0.f);
        float4 wv = *(const float4*)(Wrow + k0);
        __syncthreads();
        Xs[ld_k4 + 0][ld_row] = xv.x;
        Xs[ld_k4 + 1][ld_row] = xv.y;
        Xs[ld_k4 + 2][ld_row] = xv.z;
        Xs[ld_k4 + 3][ld_row] = xv.w;
        Ws[ld_k4 + 0][ld_row] = wv.x;
        Ws[ld_k4 + 1][ld_row] = wv.y;
        Ws[ld_k4 + 2][ld_row] = wv.z;
        Ws[ld_k4 + 3][ld_row] = wv.w;
        __syncthreads();
#pragma unroll
        for (int k = 0; k < 16; k++) {
            float4 a = *(const float4*)&Xs[k][tr * 4];
            float4 b = *(const float4*)&Ws[k][tc * 4];
            acc[0][0] += a.x * b.x; acc[0][1] += a.x * b.y; acc[0][2] += a.x * b.z; acc[0][3] += a.x * b.w;
            acc[1][0] += a.y * b.x; acc[1][1] += a.y * b.y; acc[1][2] += a.y * b.z; acc[1][3] += a.y * b.w;
            acc[2][0] += a.z * b.x; acc[2][1] += a.z * b.y; acc[2][2] += a.z * b.z; acc[2][3] += a.z * b.w;
            acc[3][0] += a.w * b.x; acc[3][1] += a.w * b.y; acc[3][2] += a.w * b.z; acc[3][3] += a.w * b.w;
        }
    }

#pragma unroll
    for (int ii = 0; ii < 4; ii++) {
        int node = n_base + tr * 4 + ii;
        if (node >= N) continue;
        float x1v = X1B ? x1[node] : 0.f;
        float vout[4];
#pragma unroll
        for (int jj = 0; jj < 4; jj++) {
            int m = m_base + tc * 4 + jj;
            float v = acc[ii][jj];
            if (X1B) v += x1v * bvec[m] + bias[m];
            else     v += bvec[m];
            if (LEAKY) v = leaky(v);
            vout[jj] = v;
        }
        if (BF16OUT) {
            ushort4 s4;
            s4.x = f2bf(vout[0]); s4.y = f2bf(vout[1]);
            s4.z = f2bf(vout[2]); s4.w = f2bf(vout[3]);
            *(ushort4*)((unsigned short*)Cv + (size_t)node * M + m_base + tc * 4) = s4;
        } else {
            *(float4*)((float*)Cv + (size_t)node * M + m_base + tc * 4) =
                make_float4(vout[0], vout[1], vout[2], vout[3]);
        }
    }
}

extern "C" void kernel_launch(void* const* d_in, const int* in_sizes, int n_in,
                              void* d_out, int out_size, void* d_ws, size_t ws_size,
                              hipStream_t stream)
{
    const int* ei       = (const int*)d_in[0];     // (2,E) int32
    const float* val    = (const float*)d_in[1];   // (E,)
    const float* w1     = (const float*)d_in[3];   // (128,1)
    const float* b1     = (const float*)d_in[4];   // (128,)
    const float* w2     = (const float*)d_in[5];   // (256,128)
    const float* b2     = (const float*)d_in[6];   // (256,)
    const float* bias2  = (const float*)d_in[7];   // (256,)
    const float* w3     = (const float*)d_in[8];   // (128,256)
    const float* b3     = (const float*)d_in[9];   // (128,)
    const float* bias3  = (const float*)d_in[10];  // (128,)
    float* out = (float*)d_out;

    const int E = in_sizes[1];
    const int N = out_size / D1;
    const int* row = ei;
    const int* col = ei + E;

    // workspace layout
    unsigned long long* rowstats8 = (unsigned long long*)d_ws;       // 8*N u64 (zeroed)
    int*   col_cnt = (int*)(rowstats8 + (size_t)8 * N);              // N (zeroed)
    float* dinv    = (float*)(col_cnt + N);                          // N
    float* pv_self = dinv + N;                                       // N
    float* x1      = pv_self + N;                                    // N
    int*   col_ptr = (int*)(x1 + N);                                 // N+1
    int*   partials= col_ptr + N + 8;                                // 64
    int*   rank    = partials + 64;                                  // E
    int2*  srt_rp  = (int2*)(rank + E);                              // E int2
    float2* px     = (float2*)(srt_rp + (size_t)E);                  // E float2
    float* p2      = (float*)(px + (size_t)E);                       // N*128 fp32
    float* h2      = p2 + (size_t)N * D1;                            // N*256 fp32
    unsigned int* zb = (unsigned int*)p2;                            // bf16 z aliases dead p2

    hipMemsetAsync(d_ws, 0, (size_t)8 * N * 8 + (size_t)N * 4, stream);

    const int B = 256;
    const int scan_blocks = (N + 2047) / 2048;

    k_edge_stats<<<(E + B - 1) / B, B, 0, stream>>>(row, col, val, rowstats8, col_cnt, rank, E, N);
    k_node_stats<<<(N + B - 1) / B, B, 0, stream>>>(rowstats8, dinv, pv_self, N);

    k_scan_local<<<scan_blocks, 256, 0, stream>>>(col_cnt, col_ptr, partials, N);
    k_scan_partials<<<1, 64, 0, stream>>>(partials, scan_blocks, col_ptr, N, E);
    k_scan_add<<<(N + B - 1) / B, B, 0, stream>>>(col_ptr, partials, N);

    k_scatter<<<(E + B - 1) / B, B, 0, stream>>>(row, col, val, dinv, col_ptr, rank, srt_rp, E);
    k_x1<<<(N + B - 1) / B, B, 0, stream>>>(col_ptr, srt_rp, pv_self, x1, N);
    k_gather_x1<<<(E + B - 1) / B, B, 0, stream>>>(srt_rp, x1, px, E);

    // conv2: scalar-form propagate, then GEMM 128->256 (fp32 out)
    k_prop2<<<(N + 1) / 2, 256, 0, stream>>>(col_ptr, px, pv_self, x1, w1, b1, p2, N);
    {
        dim3 grid((N + 63) / 64, D2 / 64);
        k_gemm_t<D1, D2, true, true, false><<<grid, 256, 0, stream>>>(p2, w2, b2, bias2, x1, h2, N);
    }

    // conv3: GEMM 256->128 -> bf16 z, then bf16 gather propagate + fused bias3/leaky
    {
        dim3 grid((N + 63) / 64, D1 / 64);
        k_gemm_t<D2, D1, false, false, true><<<grid, 256, 0, stream>>>(h2, w3, b3, nullptr, nullptr, (void*)zb, N);
    }
    k_prop3_bf16<<<(N + 3) / 4, 256, 0, stream>>>(col_ptr, srt_rp, pv_self, zb, bias3, out, N);
}